// Round 8
// baseline (74.556 us; speedup 1.0000x reference)
//
#include <hip/hip_runtime.h>
#include <hip/hip_fp16.h>

// src:  [1,2,160,192,224] f32, flow: [1,3,160,192,224] f32, out: [1,2,160,192,224] f32
constexpr int D = 160, H = 192, W = 224;
constexpr int HW = H * W;
constexpr int N = D * HW;

// Tile 8x8x56 outputs, halo 4 -> staged 16x16x64 half2 = 64 KB, double-buffered (128 KB).
// Persistent blocks (240 x 8 tiles), 1 barrier/tile:
//   issue(t+1)->regs | MEM-CLOBBER | gather(t) | commit(t+1) | barrier
constexpr int BZ = 8, BY = 8, BX = 56;
constexpr int HA = 4;
constexpr int SZ = 16, SY = 16, SX = 64;
constexpr int NTHR = 1024;
constexpr int NBLK = 240;
constexpr int NTX = 4, NTY = 24, NTZ = 20;
constexpr int NTILES = NTX * NTY * NTZ;   // 1920 = 240 * 8
constexpr int TPB = SZ * SY * SX;         // 16384 half2 per buffer

struct h2p { __half2 a, b; };             // (ch0,ch1)@x0 , (ch0,ch1)@x1
__device__ __forceinline__ h2p ld_pair(const __half2* p){ h2p v; __builtin_memcpy(&v,p,8); return v; }
__device__ __forceinline__ void st_pair(__half2* p, h2p v){ __builtin_memcpy(p,&v,8); }
__device__ __forceinline__ float2 ld2f(const float* p){ float2 v; __builtin_memcpy(&v,p,8); return v; }

struct TC {
    int tx0, ty0, tz0, tbase;
    bool xe, ye, ze;                      // axis touches volume boundary
    float bxf, byf, bzf;                  // tile output origin as float
};
__device__ __forceinline__ TC make_tc(int t) {
    TC c;
    const int bx = t & 3;
    const int q  = t >> 2;
    const int by = q % NTY;
    const int bz = q / NTY;
    c.tx0 = bx * BX - HA; c.ty0 = by * BY - HA; c.tz0 = bz * BZ - HA;
    c.xe = (bx == 0) | (bx == NTX - 1);
    c.ye = (by == 0) | (by == NTY - 1);
    c.ze = (bz == 0) | (bz == NTZ - 1);
    c.tbase = (bz * BZ * H + by * BY) * W + bx * BX;
    c.bxf = (float)(bx * BX); c.byf = (float)(by * BY); c.bzf = (float)(bz * BZ);
    return c;
}

__global__ __launch_bounds__(NTHR, 4) void warp3d_r7_kernel(
    const float* __restrict__ src,
    const float* __restrict__ flow,
    float* __restrict__ out)
{
    __shared__ __half2 tile[2][TPB];      // 128 KB

    const float* src0 = src;
    const float* src1 = src + N;
    const float* f0 = flow, * f1 = flow + N, * f2 = flow + 2 * N;
    float* out0 = out, * out1 = out + N;

    const int tid = threadIdx.x;
    const int u5  = tid & 31;             // x-pair lane
    const int rw  = tid >> 5;             // row worker 0..31
    const int tt  = rw & 15;              // staged y-row (j-invariant)
    const int sz0 = rw >> 4;              // staged z base (j adds 2)
    const bool has4 = (tid < 512);        // NVOX - 3*NTHR = 512

    // ---- tile-independent per-thread voxel map (computed ONCE) ----
    int   voff[4];
    float lxf[4], lyf[4], lzf[4];
    #pragma unroll
    for (int i = 0; i < 4; ++i) {
        const int v  = tid + i * NTHR;
        const int lx = v % BX;
        const int q  = v / BX;
        const int ly = q % BY;
        const int lz = q / BY;
        voff[i] = (lz * H + ly) * W + lx;
        lxf[i] = (float)lx; lyf[i] = (float)ly; lzf[i] = (float)lz;
    }

    float2 sA[8], sB[8];                  // staged src x-pairs (next tile)
    float fzn[4], fyn[4], fxn[4];         // flow, next tile
    float fzc[4], fyc[4], fxc[4];         // flow, current tile

    // ---- issue: all global loads for tile c into registers, no waits ----
    auto issue = [&](const TC& c) {
        const int b  = c.tx0 + (u5 << 1);
        const int bc = c.xe ? min(max(b, 0), W - 2) : b;
        int gy = c.ty0 + tt;
        if (c.ye) gy = min(max(gy, 0), H - 1);
        const int rowoff = gy * W + bc;
        if (!c.ze) {
            int ga = (c.tz0 + sz0) * HW + rowoff;
            #pragma unroll
            for (int j = 0; j < 8; ++j) {
                sA[j] = ld2f(src0 + ga);
                sB[j] = ld2f(src1 + ga);
                ga += 2 * HW;
            }
        } else {
            #pragma unroll
            for (int j = 0; j < 8; ++j) {
                const int gz = min(max(c.tz0 + sz0 + 2 * j, 0), D - 1);
                const int ga = gz * HW + rowoff;
                sA[j] = ld2f(src0 + ga);
                sB[j] = ld2f(src1 + ga);
            }
        }
        #pragma unroll
        for (int i = 0; i < 4; ++i) {
            if (i < 3 || has4) {
                const int vi = c.tbase + voff[i];
                fzn[i] = __builtin_nontemporal_load(f0 + vi);
                fyn[i] = __builtin_nontemporal_load(f1 + vi);
                fxn[i] = __builtin_nontemporal_load(f2 + vi);
            }
        }
    };

    // ---- commit: cvt + ds_write staged pairs into buffer p ----
    auto commit = [&](const TC& c, int p) {
        __half2* buf = tile[p];
        int ld = (rw << 6) + (u5 << 1);
        if (!c.xe) {
            #pragma unroll
            for (int j = 0; j < 8; ++j) {
                h2p v;
                v.a = __floats2half2_rn(sA[j].x, sB[j].x);
                v.b = __floats2half2_rn(sA[j].y, sB[j].y);
                st_pair(&buf[ld], v);
                ld += 2048;
            }
        } else {
            const int b  = c.tx0 + (u5 << 1);
            const int bc = min(max(b, 0), W - 2);
            const bool s0 = (min(max(b,     0), W - 1) > bc);
            const bool s1 = (min(max(b + 1, 0), W - 1) > bc);
            #pragma unroll
            for (int j = 0; j < 8; ++j) {
                const float a0 = s0 ? sA[j].y : sA[j].x;
                const float a1 = s1 ? sA[j].y : sA[j].x;
                const float c0 = s0 ? sB[j].y : sB[j].x;
                const float c1 = s1 ? sB[j].y : sB[j].x;
                h2p v;
                v.a = __floats2half2_rn(a0, c0);
                v.b = __floats2half2_rn(a1, c1);
                st_pair(&buf[ld], v);
                ld += 2048;
            }
        }
    };

    auto shift_flow = [&]() {
        #pragma unroll
        for (int i = 0; i < 4; ++i) { fzc[i] = fzn[i]; fyc[i] = fyn[i]; fxc[i] = fxn[i]; }
    };

    // ---- gather: 3.5 voxels/thread from LDS buffer p ----
    auto gather = [&](const TC& c, int p) {
        const __half2* buf = tile[p];
        #pragma unroll
        for (int i = 0; i < 4; ++i) {
            if (i == 3 && !has4) break;   // wave-uniform (split at tid 512)
            const int vi = c.tbase + voff[i];

            const float pz = fzc[i] + (c.bzf + lzf[i]);
            const float py = fyc[i] + (c.byf + lyf[i]);
            const float px = fxc[i] + (c.bxf + lxf[i]);

            const float z0f = floorf(pz), y0f = floorf(py), x0f = floorf(px);
            const float fz = pz - z0f, fy = py - y0f, fx = px - x0f;
            const int z0 = (int)z0f, y0 = (int)y0f, x0 = (int)x0f;

            // fast-path weights: validity checks only on boundary axes.
            // (intile on an interior axis guarantees in-volume -> check-free.)
            float wz0, wz1, wy0, wy1, wx0, wx1;
            if (c.ze) { wz0 = ((unsigned)z0 < (unsigned)D) ? (1.0f - fz) : 0.0f;
                        wz1 = ((unsigned)(z0+1) < (unsigned)D) ? fz : 0.0f; }
            else      { wz0 = 1.0f - fz; wz1 = fz; }
            if (c.ye) { wy0 = ((unsigned)y0 < (unsigned)H) ? (1.0f - fy) : 0.0f;
                        wy1 = ((unsigned)(y0+1) < (unsigned)H) ? fy : 0.0f; }
            else      { wy0 = 1.0f - fy; wy1 = fy; }
            if (c.xe) { wx0 = ((unsigned)x0 < (unsigned)W) ? (1.0f - fx) : 0.0f;
                        wx1 = ((unsigned)(x0+1) < (unsigned)W) ? fx : 0.0f; }
            else      { wx0 = 1.0f - fx; wx1 = fx; }

            const int a0 = z0 - c.tz0;
            const int b0 = y0 - c.ty0;
            const int u0 = x0 - c.tx0;
            const bool intile = ((unsigned)a0 < (unsigned)(SZ - 1)) &&
                                ((unsigned)b0 < (unsigned)(SY - 1)) &&
                                ((unsigned)u0 < (unsigned)(SX - 1));

            float acc0, acc1;
            if (intile) {
                const float w00 = wz0 * wy0, w01 = wz0 * wy1;
                const float w10 = wz1 * wy0, w11 = wz1 * wy1;
                const __half2 wxh0 = __float2half2_rn(wx0);
                const __half2 wxh1 = __float2half2_rn(wx1);

                const int r00 = (((a0 << 4) + b0) << 6) + u0;
                const h2p q00 = ld_pair(&buf[r00]);
                const h2p q01 = ld_pair(&buf[r00 + SX]);
                const h2p q10 = ld_pair(&buf[r00 + SY * SX]);
                const h2p q11 = ld_pair(&buf[r00 + SY * SX + SX]);

                // packed x-lerp: both channels in one pk-fma
                const __half2 xl00 = __hfma2(q00.b, wxh1, __hmul2(q00.a, wxh0));
                const __half2 xl01 = __hfma2(q01.b, wxh1, __hmul2(q01.a, wxh0));
                const __half2 xl10 = __hfma2(q10.b, wxh1, __hmul2(q10.a, wxh0));
                const __half2 xl11 = __hfma2(q11.b, wxh1, __hmul2(q11.a, wxh0));

                const float2 g00 = __half22float2(xl00);
                const float2 g01 = __half22float2(xl01);
                const float2 g10 = __half22float2(xl10);
                const float2 g11 = __half22float2(xl11);

                acc0 = fmaf(w11, g11.x, fmaf(w10, g10.x, fmaf(w01, g01.x, w00 * g00.x)));
                acc1 = fmaf(w11, g11.y, fmaf(w10, g10.y, fmaf(w01, g01.y, w00 * g00.y)));
            } else {
                // cold exact fallback: full-validity weights + fp32 global reads
                const float vz0 = ((unsigned)z0 < (unsigned)D) ? (1.0f - fz) : 0.0f;
                const float vz1 = ((unsigned)(z0+1) < (unsigned)D) ? fz : 0.0f;
                const float vy0 = ((unsigned)y0 < (unsigned)H) ? (1.0f - fy) : 0.0f;
                const float vy1 = ((unsigned)(y0+1) < (unsigned)H) ? fy : 0.0f;
                const float vx0 = ((unsigned)x0 < (unsigned)W) ? (1.0f - fx) : 0.0f;
                const float vx1 = ((unsigned)(x0+1) < (unsigned)W) ? fx : 0.0f;
                const float w00 = vz0 * vy0, w01 = vz0 * vy1;
                const float w10 = vz1 * vy0, w11 = vz1 * vy1;
                const int zc0 = min(max(z0, 0), D - 1), zc1 = min(max(z0 + 1, 0), D - 1);
                const int yc0 = min(max(y0, 0), H - 1), yc1 = min(max(y0 + 1, 0), H - 1);
                const int xc0 = min(max(x0, 0), W - 1), xc1 = min(max(x0 + 1, 0), W - 1);
                const int g00 = (zc0 * H + yc0) * W, g01 = (zc0 * H + yc1) * W;
                const int g10 = (zc1 * H + yc0) * W, g11 = (zc1 * H + yc1) * W;
                acc0 = w00 * (vx0 * src0[g00 + xc0] + vx1 * src0[g00 + xc1])
                     + w01 * (vx0 * src0[g01 + xc0] + vx1 * src0[g01 + xc1])
                     + w10 * (vx0 * src0[g10 + xc0] + vx1 * src0[g10 + xc1])
                     + w11 * (vx0 * src0[g11 + xc0] + vx1 * src0[g11 + xc1]);
                acc1 = w00 * (vx0 * src1[g00 + xc0] + vx1 * src1[g00 + xc1])
                     + w01 * (vx0 * src1[g01 + xc0] + vx1 * src1[g01 + xc1])
                     + w10 * (vx0 * src1[g10 + xc0] + vx1 * src1[g10 + xc1])
                     + w11 * (vx0 * src1[g11 + xc0] + vx1 * src1[g11 + xc1]);
            }

            __builtin_nontemporal_store(acc0, out0 + vi);
            __builtin_nontemporal_store(acc1, out1 + vi);
        }
    };

    // ---- persistent pipeline: one barrier per tile ----
    int tcur = blockIdx.x;
    TC cc = make_tc(tcur);
    int p = 0;
    issue(cc);
    commit(cc, 0);
    shift_flow();
    __syncthreads();                      // buf0 ready

    int tnext = tcur + NBLK;
    while (true) {
        const bool more = (tnext < NTILES);
        TC cn;
        if (more) { cn = make_tc(tnext); issue(cn); }
        // pin: issued loads may not sink below; gather's mem ops may not hoist above
        asm volatile("" ::: "memory");
        gather(cc, p);
        if (!more) break;
        commit(cn, p ^ 1);                // waits vmcnt here, writes other buffer
        shift_flow();
        __syncthreads();                  // buf p^1 ready
        cc = cn;
        tnext += NBLK;
        p ^= 1;
    }
}

extern "C" void kernel_launch(void* const* d_in, const int* in_sizes, int n_in,
                              void* d_out, int out_size, void* d_ws, size_t ws_size,
                              hipStream_t stream) {
    const float* src  = (const float*)d_in[0];
    const float* flow = (const float*)d_in[1];
    float* out = (float*)d_out;

    warp3d_r7_kernel<<<NBLK, NTHR, 0, stream>>>(src, flow, out);
}

// Round 9
// 70.518 us; speedup vs baseline: 1.0573x; 1.0573x over previous
//
#include <hip/hip_runtime.h>
#include <hip/hip_fp16.h>

// src:  [1,2,160,192,224] f32, flow: [1,3,160,192,224] f32, out: [1,2,160,192,224] f32
constexpr int D = 160, H = 192, W = 224;
constexpr int HW = H * W;
constexpr int N = D * HW;

// Tile 8x8x56 outputs, halo 4 -> staged 16x16x64 half2 = 64 KB, double-buffered (128 KB).
// Persistent blocks (240 x 8 tiles), 1 barrier/tile:
//   issue(t+1)->regs | MEM-CLOBBER | gather(t) | commit(t+1) | barrier
constexpr int BZ = 8, BY = 8, BX = 56;
constexpr int HA = 4;
constexpr int SZ = 16, SY = 16, SX = 64;
constexpr int NTHR = 1024;
constexpr int NBLK = 240;
constexpr int NTX = 4, NTY = 24, NTZ = 20;
constexpr int NTILES = NTX * NTY * NTZ;   // 1920 = 240 * 8
constexpr int TPB = SZ * SY * SX;         // 16384 half2 per buffer

struct h2p { __half2 a, b; };             // (ch0,ch1)@x0 , (ch0,ch1)@x1
__device__ __forceinline__ h2p ld_pair(const __half2* p){ h2p v; __builtin_memcpy(&v,p,8); return v; }
__device__ __forceinline__ void st_pair(__half2* p, h2p v){ __builtin_memcpy(p,&v,8); }
__device__ __forceinline__ float2 ld2f(const float* p){ float2 v; __builtin_memcpy(&v,p,8); return v; }

struct TC {
    int tx0, ty0, tz0, tbase;
    bool xe, ye, ze;                      // axis touches volume boundary
    float bxf, byf, bzf;                  // tile output origin as float
};
__device__ __forceinline__ TC make_tc(int t) {
    TC c;
    const int bx = t & 3;
    const int q  = t >> 2;
    const int by = q % NTY;
    const int bz = q / NTY;
    c.tx0 = bx * BX - HA; c.ty0 = by * BY - HA; c.tz0 = bz * BZ - HA;
    c.xe = (bx == 0) | (bx == NTX - 1);
    c.ye = (by == 0) | (by == NTY - 1);
    c.ze = (bz == 0) | (bz == NTZ - 1);
    c.tbase = (bz * BZ * H + by * BY) * W + bx * BX;
    c.bxf = (float)(bx * BX); c.byf = (float)(by * BY); c.bzf = (float)(bz * BZ);
    return c;
}

__global__ __launch_bounds__(NTHR, 4) void warp3d_r8_kernel(
    const float* __restrict__ src,
    const float* __restrict__ flow,
    float* __restrict__ out)
{
    __shared__ __half2 tile[2][TPB];      // 128 KB

    const float* src0 = src;
    const float* src1 = src + N;
    const float* f0 = flow, * f1 = flow + N, * f2 = flow + 2 * N;
    float* out0 = out, * out1 = out + N;

    const int tid = threadIdx.x;
    const int u5  = tid & 31;             // x-pair lane
    const int rw  = tid >> 5;             // row worker 0..31
    const int tt  = rw & 15;              // staged y-row (j-invariant)
    const int sz0 = rw >> 4;              // staged z base (j adds 2)
    const bool has4 = (tid < 512);        // NVOX - 3*NTHR = 512

    // ---- tile-independent per-thread voxel map (computed ONCE) ----
    int   voff[4];
    float lxf[4], lyf[4], lzf[4];
    #pragma unroll
    for (int i = 0; i < 4; ++i) {
        const int v  = tid + i * NTHR;
        const int lx = v % BX;
        const int q  = v / BX;
        const int ly = q % BY;
        const int lz = q / BY;
        voff[i] = (lz * H + ly) * W + lx;
        lxf[i] = (float)lx; lyf[i] = (float)ly; lzf[i] = (float)lz;
    }

    float2 sA[8], sB[8];                  // staged src x-pairs (next tile)
    float fzn[4], fyn[4], fxn[4];         // flow, next tile
    float fzc[4], fyc[4], fxc[4];         // flow, current tile

    // ---- issue: all global loads for tile c into registers, no waits ----
    auto issue = [&](const TC& c) {
        const int b  = c.tx0 + (u5 << 1);
        const int bc = c.xe ? min(max(b, 0), W - 2) : b;
        int gy = c.ty0 + tt;
        if (c.ye) gy = min(max(gy, 0), H - 1);
        const int rowoff = gy * W + bc;
        if (!c.ze) {
            int ga = (c.tz0 + sz0) * HW + rowoff;
            #pragma unroll
            for (int j = 0; j < 8; ++j) {
                sA[j] = ld2f(src0 + ga);
                sB[j] = ld2f(src1 + ga);
                ga += 2 * HW;
            }
        } else {
            #pragma unroll
            for (int j = 0; j < 8; ++j) {
                const int gz = min(max(c.tz0 + sz0 + 2 * j, 0), D - 1);
                const int ga = gz * HW + rowoff;
                sA[j] = ld2f(src0 + ga);
                sB[j] = ld2f(src1 + ga);
            }
        }
        #pragma unroll
        for (int i = 0; i < 4; ++i) {
            if (i < 3 || has4) {
                const int vi = c.tbase + voff[i];
                fzn[i] = f0[vi];
                fyn[i] = f1[vi];
                fxn[i] = f2[vi];
            }
        }
    };

    // ---- commit: cvt + ds_write staged pairs into buffer p ----
    auto commit = [&](const TC& c, int p) {
        __half2* buf = tile[p];
        int ld = (rw << 6) + (u5 << 1);
        if (!c.xe) {
            #pragma unroll
            for (int j = 0; j < 8; ++j) {
                h2p v;
                v.a = __floats2half2_rn(sA[j].x, sB[j].x);
                v.b = __floats2half2_rn(sA[j].y, sB[j].y);
                st_pair(&buf[ld], v);
                ld += 2048;
            }
        } else {
            const int b  = c.tx0 + (u5 << 1);
            const int bc = min(max(b, 0), W - 2);
            const bool s0 = (min(max(b,     0), W - 1) > bc);
            const bool s1 = (min(max(b + 1, 0), W - 1) > bc);
            #pragma unroll
            for (int j = 0; j < 8; ++j) {
                const float a0 = s0 ? sA[j].y : sA[j].x;
                const float a1 = s1 ? sA[j].y : sA[j].x;
                const float c0 = s0 ? sB[j].y : sB[j].x;
                const float c1 = s1 ? sB[j].y : sB[j].x;
                h2p v;
                v.a = __floats2half2_rn(a0, c0);
                v.b = __floats2half2_rn(a1, c1);
                st_pair(&buf[ld], v);
                ld += 2048;
            }
        }
    };

    auto shift_flow = [&]() {
        #pragma unroll
        for (int i = 0; i < 4; ++i) { fzc[i] = fzn[i]; fyc[i] = fyn[i]; fxc[i] = fxn[i]; }
    };

    // ---- gather: 3.5 voxels/thread from LDS buffer p ----
    auto gather = [&](const TC& c, int p) {
        const __half2* buf = tile[p];
        #pragma unroll
        for (int i = 0; i < 4; ++i) {
            if (i == 3 && !has4) break;   // wave-uniform (split at tid 512)
            const int vi = c.tbase + voff[i];

            const float pz = fzc[i] + (c.bzf + lzf[i]);
            const float py = fyc[i] + (c.byf + lyf[i]);
            const float px = fxc[i] + (c.bxf + lxf[i]);

            const float z0f = floorf(pz), y0f = floorf(py), x0f = floorf(px);
            const float fz = pz - z0f, fy = py - y0f, fx = px - x0f;
            const int z0 = (int)z0f, y0 = (int)y0f, x0 = (int)x0f;

            // fast-path weights: validity checks only on boundary axes.
            float wz0, wz1, wy0, wy1, wx0, wx1;
            if (c.ze) { wz0 = ((unsigned)z0 < (unsigned)D) ? (1.0f - fz) : 0.0f;
                        wz1 = ((unsigned)(z0+1) < (unsigned)D) ? fz : 0.0f; }
            else      { wz0 = 1.0f - fz; wz1 = fz; }
            if (c.ye) { wy0 = ((unsigned)y0 < (unsigned)H) ? (1.0f - fy) : 0.0f;
                        wy1 = ((unsigned)(y0+1) < (unsigned)H) ? fy : 0.0f; }
            else      { wy0 = 1.0f - fy; wy1 = fy; }
            if (c.xe) { wx0 = ((unsigned)x0 < (unsigned)W) ? (1.0f - fx) : 0.0f;
                        wx1 = ((unsigned)(x0+1) < (unsigned)W) ? fx : 0.0f; }
            else      { wx0 = 1.0f - fx; wx1 = fx; }

            const int a0 = z0 - c.tz0;
            const int b0 = y0 - c.ty0;
            const int u0 = x0 - c.tx0;
            const bool intile = ((unsigned)a0 < (unsigned)(SZ - 1)) &&
                                ((unsigned)b0 < (unsigned)(SY - 1)) &&
                                ((unsigned)u0 < (unsigned)(SX - 1));

            float acc0, acc1;
            if (intile) {
                const float w00 = wz0 * wy0, w01 = wz0 * wy1;
                const float w10 = wz1 * wy0, w11 = wz1 * wy1;
                const __half2 wxh0 = __float2half2_rn(wx0);
                const __half2 wxh1 = __float2half2_rn(wx1);

                const int r00 = (((a0 << 4) + b0) << 6) + u0;
                const h2p q00 = ld_pair(&buf[r00]);
                const h2p q01 = ld_pair(&buf[r00 + SX]);
                const h2p q10 = ld_pair(&buf[r00 + SY * SX]);
                const h2p q11 = ld_pair(&buf[r00 + SY * SX + SX]);

                // packed x-lerp: both channels in one pk-fma
                const __half2 xl00 = __hfma2(q00.b, wxh1, __hmul2(q00.a, wxh0));
                const __half2 xl01 = __hfma2(q01.b, wxh1, __hmul2(q01.a, wxh0));
                const __half2 xl10 = __hfma2(q10.b, wxh1, __hmul2(q10.a, wxh0));
                const __half2 xl11 = __hfma2(q11.b, wxh1, __hmul2(q11.a, wxh0));

                const float2 g00 = __half22float2(xl00);
                const float2 g01 = __half22float2(xl01);
                const float2 g10 = __half22float2(xl10);
                const float2 g11 = __half22float2(xl11);

                acc0 = fmaf(w11, g11.x, fmaf(w10, g10.x, fmaf(w01, g01.x, w00 * g00.x)));
                acc1 = fmaf(w11, g11.y, fmaf(w10, g10.y, fmaf(w01, g01.y, w00 * g00.y)));
            } else {
                // cold exact fallback: full-validity weights + fp32 global reads
                const float vz0 = ((unsigned)z0 < (unsigned)D) ? (1.0f - fz) : 0.0f;
                const float vz1 = ((unsigned)(z0+1) < (unsigned)D) ? fz : 0.0f;
                const float vy0 = ((unsigned)y0 < (unsigned)H) ? (1.0f - fy) : 0.0f;
                const float vy1 = ((unsigned)(y0+1) < (unsigned)H) ? fy : 0.0f;
                const float vx0 = ((unsigned)x0 < (unsigned)W) ? (1.0f - fx) : 0.0f;
                const float vx1 = ((unsigned)(x0+1) < (unsigned)W) ? fx : 0.0f;
                const float w00 = vz0 * vy0, w01 = vz0 * vy1;
                const float w10 = vz1 * vy0, w11 = vz1 * vy1;
                const int zc0 = min(max(z0, 0), D - 1), zc1 = min(max(z0 + 1, 0), D - 1);
                const int yc0 = min(max(y0, 0), H - 1), yc1 = min(max(y0 + 1, 0), H - 1);
                const int xc0 = min(max(x0, 0), W - 1), xc1 = min(max(x0 + 1, 0), W - 1);
                const int g00 = (zc0 * H + yc0) * W, g01 = (zc0 * H + yc1) * W;
                const int g10 = (zc1 * H + yc0) * W, g11 = (zc1 * H + yc1) * W;
                acc0 = w00 * (vx0 * src0[g00 + xc0] + vx1 * src0[g00 + xc1])
                     + w01 * (vx0 * src0[g01 + xc0] + vx1 * src0[g01 + xc1])
                     + w10 * (vx0 * src0[g10 + xc0] + vx1 * src0[g10 + xc1])
                     + w11 * (vx0 * src0[g11 + xc0] + vx1 * src0[g11 + xc1]);
                acc1 = w00 * (vx0 * src1[g00 + xc0] + vx1 * src1[g00 + xc1])
                     + w01 * (vx0 * src1[g01 + xc0] + vx1 * src1[g01 + xc1])
                     + w10 * (vx0 * src1[g10 + xc0] + vx1 * src1[g10 + xc1])
                     + w11 * (vx0 * src1[g11 + xc0] + vx1 * src1[g11 + xc1]);
            }

            out0[vi] = acc0;
            out1[vi] = acc1;
        }
    };

    // ---- persistent pipeline: one barrier per tile ----
    int tcur = blockIdx.x;
    TC cc = make_tc(tcur);
    int p = 0;
    issue(cc);
    commit(cc, 0);
    shift_flow();
    __syncthreads();                      // buf0 ready

    int tnext = tcur + NBLK;
    while (true) {
        const bool more = (tnext < NTILES);
        TC cn;
        if (more) { cn = make_tc(tnext); issue(cn); }
        // pin: issued loads may not sink below; gather's mem ops may not hoist above
        asm volatile("" ::: "memory");
        gather(cc, p);
        if (!more) break;
        commit(cn, p ^ 1);                // waits vmcnt here, writes other buffer
        shift_flow();
        __syncthreads();                  // buf p^1 ready
        cc = cn;
        tnext += NBLK;
        p ^= 1;
    }
}

extern "C" void kernel_launch(void* const* d_in, const int* in_sizes, int n_in,
                              void* d_out, int out_size, void* d_ws, size_t ws_size,
                              hipStream_t stream) {
    const float* src  = (const float*)d_in[0];
    const float* flow = (const float*)d_in[1];
    float* out = (float*)d_out;

    warp3d_r8_kernel<<<NBLK, NTHR, 0, stream>>>(src, flow, out);
}

// Round 10
// 70.515 us; speedup vs baseline: 1.0573x; 1.0000x over previous
//
#include <hip/hip_runtime.h>
#include <hip/hip_fp16.h>

// src:  [1,2,160,192,224] f32, flow: [1,3,160,192,224] f32, out: [1,2,160,192,224] f32
constexpr int D = 160, H = 192, W = 224;
constexpr int HW = H * W;
constexpr int N = D * HW;

// Tile 8x8x56 outputs, halo 4 -> staged 16x16x64 half2 = 64 KB, SINGLE buffer.
// Persistent 240 blocks x 8 tiles, R5 skeleton (2 barriers/tile):
//   issue(t+1)->regs | gather(t) quad-vectorized | sync | commit(t+1) | sync
constexpr int BZ = 8, BY = 8, BX = 56;
constexpr int HA = 4;
constexpr int SZ = 16, SY = 16, SX = 64;
constexpr int NTHR = 1024;
constexpr int NQ   = 896;                 // quad-owning threads (3584 vox / 4)
constexpr int NBLK = 240;
constexpr int NTX = 4, NTY = 24, NTZ = 20;
constexpr int NTILES = NTX * NTY * NTZ;   // 1920 = 240 * 8
constexpr int TPB = SZ * SY * SX;         // 16384 half2 = 64 KB

typedef float f4 __attribute__((ext_vector_type(4)));

struct h2p { __half2 a, b; };             // (ch0,ch1)@x , (ch0,ch1)@x+1
__device__ __forceinline__ h2p   ld_pair(const __half2* p){ h2p v; __builtin_memcpy(&v,p,8); return v; }
__device__ __forceinline__ void  st_pair(__half2* p, h2p v){ __builtin_memcpy(p,&v,8); }
__device__ __forceinline__ float2 ld2f(const float* p){ float2 v; __builtin_memcpy(&v,p,8); return v; }
__device__ __forceinline__ f4    ld4f(const float* p){ f4 v; __builtin_memcpy(&v,p,16); return v; }
__device__ __forceinline__ void  st4f(float* p, f4 v){ __builtin_memcpy(p,&v,16); }

struct TC {
    int tx0, ty0, tz0, tbase;
    bool xe, ye, ze;
    float bxf, byf, bzf;
};
__device__ __forceinline__ TC make_tc(int t) {
    TC c;
    const int bx = t & 3;
    const int q  = t >> 2;
    const int by = q % NTY;
    const int bz = q / NTY;
    c.tx0 = bx * BX - HA; c.ty0 = by * BY - HA; c.tz0 = bz * BZ - HA;
    c.xe = (bx == 0) | (bx == NTX - 1);
    c.ye = (by == 0) | (by == NTY - 1);
    c.ze = (bz == 0) | (bz == NTZ - 1);
    c.tbase = (bz * BZ * H + by * BY) * W + bx * BX;
    c.bxf = (float)(bx * BX); c.byf = (float)(by * BY); c.bzf = (float)(bz * BZ);
    return c;
}

__global__ __launch_bounds__(NTHR, 4) void warp3d_r9_kernel(
    const float* __restrict__ src,
    const float* __restrict__ flow,
    float* __restrict__ out)
{
    __shared__ __half2 tile[TPB];         // 64 KB

    const float* src0 = src;
    const float* src1 = src + N;
    const float* f0 = flow, * f1 = flow + N, * f2 = flow + 2 * N;
    float* out0 = out, * out1 = out + N;

    const int tid = threadIdx.x;
    const int u5  = tid & 31;             // staging x-pair lane
    const int rw  = tid >> 5;             // staging row worker 0..31
    const int tt  = rw & 15;              // staged y-row (j-invariant)
    const int sz0 = rw >> 4;              // staged z base (j adds 2)
    const bool hasq = (tid < NQ);         // wave-uniform: 896 = 14 waves

    // ---- quad map (tile-independent, computed once): 4 consecutive x per thread ----
    const int qm = tid % 14, qd = tid / 14;       // qd in [0,64) for tid<896
    const int lx = qm << 2, ly = qd & 7, lz = qd >> 3;
    const int voffq = (lz * H + ly) * W + lx;
    const float lxf = (float)lx, lyf = (float)ly, lzf = (float)lz;

    float2 sA[8], sB[8];                  // staged src x-pairs (next tile)
    f4 fz4n, fy4n, fx4n;                  // flow quad, next tile
    f4 fz4c, fy4c, fx4c;                  // flow quad, current tile

    // ---- issue: all global loads for tile c into registers, no waits ----
    auto issue = [&](const TC& c) {
        const int b  = c.tx0 + (u5 << 1);
        const int bc = c.xe ? min(max(b, 0), W - 2) : b;
        int gy = c.ty0 + tt;
        if (c.ye) gy = min(max(gy, 0), H - 1);
        const int rowoff = gy * W + bc;
        if (!c.ze) {
            int ga = (c.tz0 + sz0) * HW + rowoff;
            #pragma unroll
            for (int j = 0; j < 8; ++j) {
                sA[j] = ld2f(src0 + ga);
                sB[j] = ld2f(src1 + ga);
                ga += 2 * HW;
            }
        } else {
            #pragma unroll
            for (int j = 0; j < 8; ++j) {
                const int gz = min(max(c.tz0 + sz0 + 2 * j, 0), D - 1);
                const int ga = gz * HW + rowoff;
                sA[j] = ld2f(src0 + ga);
                sB[j] = ld2f(src1 + ga);
            }
        }
        if (hasq) {
            const int vi = c.tbase + voffq;       // 16B aligned
            fz4n = ld4f(f0 + vi);
            fy4n = ld4f(f1 + vi);
            fx4n = ld4f(f2 + vi);
        }
    };

    // ---- commit: cvt + ds_write staged pairs (waits loads via compiler vmcnt) ----
    auto commit = [&](const TC& c) {
        int ld = (rw << 6) + (u5 << 1);
        if (!c.xe) {
            #pragma unroll
            for (int j = 0; j < 8; ++j) {
                h2p v;
                v.a = __floats2half2_rn(sA[j].x, sB[j].x);
                v.b = __floats2half2_rn(sA[j].y, sB[j].y);
                st_pair(&tile[ld], v);
                ld += 2048;
            }
        } else {
            const int b  = c.tx0 + (u5 << 1);
            const int bc = min(max(b, 0), W - 2);
            const bool s0 = (min(max(b,     0), W - 1) > bc);
            const bool s1 = (min(max(b + 1, 0), W - 1) > bc);
            #pragma unroll
            for (int j = 0; j < 8; ++j) {
                const float a0 = s0 ? sA[j].y : sA[j].x;
                const float a1 = s1 ? sA[j].y : sA[j].x;
                const float c0 = s0 ? sB[j].y : sB[j].x;
                const float c1 = s1 ? sB[j].y : sB[j].x;
                h2p v;
                v.a = __floats2half2_rn(a0, c0);
                v.b = __floats2half2_rn(a1, c1);
                st_pair(&tile[ld], v);
                ld += 2048;
            }
        }
    };

    auto shift_flow = [&]() { fz4c = fz4n; fy4c = fy4n; fx4c = fx4n; };

    // ---- gather: one x-quad per thread (tid<896), float4 out stores ----
    auto gather = [&](const TC& c) {
        if (!hasq) return;                // last 2 waves: staging-only
        const int vi = c.tbase + voffq;

        const float pz_b = c.bzf + lzf;
        const float py_b = c.byf + lyf;
        const float px_b = c.bxf + lxf;

        float a0s[4], a1s[4];

        #pragma unroll
        for (int i = 0; i < 4; ++i) {
            const float pz = fz4c[i] + pz_b;
            const float py = fy4c[i] + py_b;
            const float px = fx4c[i] + (px_b + (float)i);

            const float z0f = floorf(pz), y0f = floorf(py), x0f = floorf(px);
            const float fz = pz - z0f, fy = py - y0f, fx = px - x0f;
            const int z0 = (int)z0f, y0 = (int)y0f, x0 = (int)x0f;

            float wz0, wz1, wy0, wy1, wx0, wx1;
            if (c.ze) { wz0 = ((unsigned)z0 < (unsigned)D) ? (1.0f - fz) : 0.0f;
                        wz1 = ((unsigned)(z0+1) < (unsigned)D) ? fz : 0.0f; }
            else      { wz0 = 1.0f - fz; wz1 = fz; }
            if (c.ye) { wy0 = ((unsigned)y0 < (unsigned)H) ? (1.0f - fy) : 0.0f;
                        wy1 = ((unsigned)(y0+1) < (unsigned)H) ? fy : 0.0f; }
            else      { wy0 = 1.0f - fy; wy1 = fy; }
            if (c.xe) { wx0 = ((unsigned)x0 < (unsigned)W) ? (1.0f - fx) : 0.0f;
                        wx1 = ((unsigned)(x0+1) < (unsigned)W) ? fx : 0.0f; }
            else      { wx0 = 1.0f - fx; wx1 = fx; }

            const int a0 = z0 - c.tz0;
            const int b0 = y0 - c.ty0;
            const int u0 = x0 - c.tx0;
            const bool intile = ((unsigned)a0 < (unsigned)(SZ - 1)) &&
                                ((unsigned)b0 < (unsigned)(SY - 1)) &&
                                ((unsigned)u0 < (unsigned)(SX - 1));

            if (intile) {
                const float w00 = wz0 * wy0, w01 = wz0 * wy1;
                const float w10 = wz1 * wy0, w11 = wz1 * wy1;
                const __half2 wxh0 = __float2half2_rn(wx0);
                const __half2 wxh1 = __float2half2_rn(wx1);

                const int r00 = (((a0 << 4) + b0) << 6) + u0;
                const h2p q00 = ld_pair(&tile[r00]);
                const h2p q01 = ld_pair(&tile[r00 + SX]);
                const h2p q10 = ld_pair(&tile[r00 + SY * SX]);
                const h2p q11 = ld_pair(&tile[r00 + SY * SX + SX]);

                const __half2 xl00 = __hfma2(q00.b, wxh1, __hmul2(q00.a, wxh0));
                const __half2 xl01 = __hfma2(q01.b, wxh1, __hmul2(q01.a, wxh0));
                const __half2 xl10 = __hfma2(q10.b, wxh1, __hmul2(q10.a, wxh0));
                const __half2 xl11 = __hfma2(q11.b, wxh1, __hmul2(q11.a, wxh0));

                const float2 g00 = __half22float2(xl00);
                const float2 g01 = __half22float2(xl01);
                const float2 g10 = __half22float2(xl10);
                const float2 g11 = __half22float2(xl11);

                a0s[i] = fmaf(w11, g11.x, fmaf(w10, g10.x, fmaf(w01, g01.x, w00 * g00.x)));
                a1s[i] = fmaf(w11, g11.y, fmaf(w10, g10.y, fmaf(w01, g01.y, w00 * g00.y)));
            } else {
                // cold exact fallback: full-validity weights + fp32 global reads
                const float vz0 = ((unsigned)z0 < (unsigned)D) ? (1.0f - fz) : 0.0f;
                const float vz1 = ((unsigned)(z0+1) < (unsigned)D) ? fz : 0.0f;
                const float vy0 = ((unsigned)y0 < (unsigned)H) ? (1.0f - fy) : 0.0f;
                const float vy1 = ((unsigned)(y0+1) < (unsigned)H) ? fy : 0.0f;
                const float vx0 = ((unsigned)x0 < (unsigned)W) ? (1.0f - fx) : 0.0f;
                const float vx1 = ((unsigned)(x0+1) < (unsigned)W) ? fx : 0.0f;
                const float w00 = vz0 * vy0, w01 = vz0 * vy1;
                const float w10 = vz1 * vy0, w11 = vz1 * vy1;
                const int zc0 = min(max(z0, 0), D - 1), zc1 = min(max(z0 + 1, 0), D - 1);
                const int yc0 = min(max(y0, 0), H - 1), yc1 = min(max(y0 + 1, 0), H - 1);
                const int xc0 = min(max(x0, 0), W - 1), xc1 = min(max(x0 + 1, 0), W - 1);
                const int g00 = (zc0 * H + yc0) * W, g01 = (zc0 * H + yc1) * W;
                const int g10 = (zc1 * H + yc0) * W, g11 = (zc1 * H + yc1) * W;
                a0s[i] = w00 * (vx0 * src0[g00 + xc0] + vx1 * src0[g00 + xc1])
                       + w01 * (vx0 * src0[g01 + xc0] + vx1 * src0[g01 + xc1])
                       + w10 * (vx0 * src0[g10 + xc0] + vx1 * src0[g10 + xc1])
                       + w11 * (vx0 * src0[g11 + xc0] + vx1 * src0[g11 + xc1]);
                a1s[i] = w00 * (vx0 * src1[g00 + xc0] + vx1 * src1[g00 + xc1])
                       + w01 * (vx0 * src1[g01 + xc0] + vx1 * src1[g01 + xc1])
                       + w10 * (vx0 * src1[g10 + xc0] + vx1 * src1[g10 + xc1])
                       + w11 * (vx0 * src1[g11 + xc0] + vx1 * src1[g11 + xc1]);
            }
        }

        f4 o0 = { a0s[0], a0s[1], a0s[2], a0s[3] };
        f4 o1 = { a1s[0], a1s[1], a1s[2], a1s[3] };
        st4f(out0 + vi, o0);
        st4f(out1 + vi, o1);
    };

    // ---- persistent pipeline (R5 skeleton): 2 barriers/tile ----
    int tcur = blockIdx.x;
    TC cc = make_tc(tcur);
    issue(cc);
    commit(cc);
    shift_flow();
    __syncthreads();                      // buf ready

    int tnext = tcur + NBLK;
    while (true) {
        const bool more = (tnext < NTILES);
        TC cn;
        if (more) { cn = make_tc(tnext); issue(cn); }
        asm volatile("" ::: "memory");    // keep prefetch issued before gather
        gather(cc);
        if (!more) break;
        __syncthreads();                  // all done reading buf
        commit(cn);                       // vmcnt waits land here
        shift_flow();
        __syncthreads();                  // buf ready
        cc = cn;
        tnext += NBLK;
    }
}

extern "C" void kernel_launch(void* const* d_in, const int* in_sizes, int n_in,
                              void* d_out, int out_size, void* d_ws, size_t ws_size,
                              hipStream_t stream) {
    const float* src  = (const float*)d_in[0];
    const float* flow = (const float*)d_in[1];
    float* out = (float*)d_out;

    warp3d_r9_kernel<<<NBLK, NTHR, 0, stream>>>(src, flow, out);
}

// Round 11
// 63.381 us; speedup vs baseline: 1.1763x; 1.1126x over previous
//
#include <hip/hip_runtime.h>
#include <hip/hip_fp16.h>

// src:  [1,2,160,192,224] f32, flow: [1,3,160,192,224] f32, out: [1,2,160,192,224] f32
constexpr int D = 160, H = 192, W = 224;
constexpr int HW = H * W;
constexpr int N = D * HW;

// Tile 8x8x56 outputs, halo 4 -> staged 16x16x64 half2 = 64 KB, SINGLE buffer.
// Persistent 240 blocks x 8 tiles, R5 skeleton (2 barriers/tile, NO asm clobber):
//   issue(t+1)->regs | gather(t) | sync | commit(t+1) | sync
constexpr int BZ = 8, BY = 8, BX = 56;
constexpr int HA = 4;
constexpr int SZ = 16, SY = 16, SX = 64;
constexpr int NTHR = 1024;
constexpr int NQ   = 896;                 // quad-owning threads (3584 vox / 4)
constexpr int NBLK = 240;
constexpr int NTY = 24;
constexpr int NTILES = 1920;              // 4 x 24 x 20 = 240 * 8
constexpr int TPB = SZ * SY * SX;         // 16384 half2 = 64 KB

typedef float f4 __attribute__((ext_vector_type(4)));

struct h2p { __half2 a, b; };             // (ch0,ch1)@x , (ch0,ch1)@x+1
__device__ __forceinline__ h2p    ld_pair(const __half2* p){ h2p v; __builtin_memcpy(&v,p,8); return v; }
__device__ __forceinline__ void   st_pair(__half2* p, h2p v){ __builtin_memcpy(p,&v,8); }
__device__ __forceinline__ float2 ld2f(const float* p){ float2 v; __builtin_memcpy(&v,p,8); return v; }
__device__ __forceinline__ f4     ld4f(const float* p){ f4 v; __builtin_memcpy(&v,p,16); return v; }
__device__ __forceinline__ void   st4f(float* p, f4 v){ __builtin_memcpy(p,&v,16); }

__global__ __launch_bounds__(NTHR, 4) void warp3d_r10_kernel(
    const float* __restrict__ src,
    const float* __restrict__ flow,
    float* __restrict__ out)
{
    __shared__ __half2 tile[TPB];         // 64 KB

    const float* src0 = src;
    const float* src1 = src + N;
    const float* f0 = flow, * f1 = flow + N, * f2 = flow + 2 * N;
    float* out0 = out, * out1 = out + N;

    const int tid = threadIdx.x;
    const int u5  = tid & 31;             // staging x-pair lane
    const int rw  = tid >> 5;             // staging row worker 0..31 (8 rows each)
    const bool hasq = (tid < NQ);         // wave-uniform: waves 14,15 stage-only

    // ---- quad map (tile-independent): 4 consecutive x per thread ----
    const int qm = tid % 14, qd = tid / 14;       // qd in [0,64) when tid<896
    const int lx = qm << 2, ly = qd & 7, lz = qd >> 3;
    const int voffq = (lz * H + ly) * W + lx;
    const float lxf = (float)lx, lyf = (float)ly, lzf = (float)lz;

    float2 sA[8], sB[8];                  // staged src x-pairs (next tile)
    f4 fz4n, fy4n, fx4n;                  // flow quad, next tile
    f4 fz4c, fy4c, fx4c;                  // flow quad, current tile

    // ---- issue: all global loads for tile t into registers, no waits ----
    auto issue = [&](int t) {
        const int bx = t & 3; const int q = t >> 2;
        const int by = q % NTY; const int bz = q / NTY;
        const int tz0 = bz * BZ - HA, ty0 = by * BY - HA, tx0 = bx * BX - HA;
        const int b  = tx0 + (u5 << 1);
        const int bc = min(max(b, 0), W - 2);
        #pragma unroll
        for (int j = 0; j < 8; ++j) {
            const int r  = rw + (j << 5);           // 0..255
            const int gz = min(max(tz0 + (r >> 4), 0), D - 1);
            const int gy = min(max(ty0 + (r & 15), 0), H - 1);
            const int ga = (gz * H + gy) * W + bc;
            sA[j] = ld2f(src0 + ga);
            sB[j] = ld2f(src1 + ga);
        }
        if (hasq) {
            const int vi = (bz * BZ * H + by * BY) * W + bx * BX + voffq;  // 16B aligned
            fz4n = ld4f(f0 + vi);
            fy4n = ld4f(f1 + vi);
            fx4n = ld4f(f2 + vi);
        }
    };

    // ---- commit: cvt + ds_write staged pairs (compiler inserts vmcnt waits) ----
    auto commit = [&](int t) {
        const int bx = t & 3;
        const int tx0 = bx * BX - HA;
        const int b   = tx0 + (u5 << 1);
        const int bc  = min(max(b, 0), W - 2);
        const bool s0 = (min(max(b,     0), W - 1) > bc);   // x-edge component select
        const bool s1 = (min(max(b + 1, 0), W - 1) > bc);
        int ld = (rw << 6) + (u5 << 1);
        #pragma unroll
        for (int j = 0; j < 8; ++j) {
            const float a0 = s0 ? sA[j].y : sA[j].x;
            const float a1 = s1 ? sA[j].y : sA[j].x;
            const float c0 = s0 ? sB[j].y : sB[j].x;
            const float c1 = s1 ? sB[j].y : sB[j].x;
            h2p v;
            v.a = __floats2half2_rn(a0, c0);
            v.b = __floats2half2_rn(a1, c1);
            st_pair(&tile[ld], v);
            ld += 2048;                                     // 32 rows * 64
        }
    };

    auto shift_flow = [&]() { fz4c = fz4n; fy4c = fy4n; fx4c = fx4n; };

    // ---- gather: one x-quad per thread (tid<896), float4 out stores ----
    auto gather = [&](int t) {
        if (!hasq) return;
        const int bx = t & 3; const int q = t >> 2;
        const int by = q % NTY; const int bz = q / NTY;
        const int tz0 = bz * BZ - HA, ty0 = by * BY - HA, tx0 = bx * BX - HA;
        const int vi = (bz * BZ * H + by * BY) * W + bx * BX + voffq;

        const float pz_b = (float)(bz * BZ) + lzf;
        const float py_b = (float)(by * BY) + lyf;
        const float px_b = (float)(bx * BX) + lxf;

        float a0s[4], a1s[4];

        #pragma unroll
        for (int i = 0; i < 4; ++i) {
            const float pz = fz4c[i] + pz_b;
            const float py = fy4c[i] + py_b;
            const float px = fx4c[i] + (px_b + (float)i);

            const float z0f = floorf(pz), y0f = floorf(py), x0f = floorf(px);
            const float fz = pz - z0f, fy = py - y0f, fx = px - x0f;
            const int z0 = (int)z0f, y0 = (int)y0f, x0 = (int)x0f;

            // zeros padding folded into per-axis weights (validity on GLOBAL coords)
            const float wz0 = ((unsigned)z0       < (unsigned)D) ? (1.0f - fz) : 0.0f;
            const float wz1 = ((unsigned)(z0 + 1) < (unsigned)D) ? fz          : 0.0f;
            const float wy0 = ((unsigned)y0       < (unsigned)H) ? (1.0f - fy) : 0.0f;
            const float wy1 = ((unsigned)(y0 + 1) < (unsigned)H) ? fy          : 0.0f;
            const float wx0 = ((unsigned)x0       < (unsigned)W) ? (1.0f - fx) : 0.0f;
            const float wx1 = ((unsigned)(x0 + 1) < (unsigned)W) ? fx          : 0.0f;

            const float w00 = wz0 * wy0, w01 = wz0 * wy1;
            const float w10 = wz1 * wy0, w11 = wz1 * wy1;

            const int a0 = z0 - tz0;
            const int b0 = y0 - ty0;
            const int u0 = x0 - tx0;
            const bool intile = ((unsigned)a0 < (unsigned)(SZ - 1)) &&
                                ((unsigned)b0 < (unsigned)(SY - 1)) &&
                                ((unsigned)u0 < (unsigned)(SX - 1));

            if (intile) {
                const int r00 = (((a0 << 4) + b0) << 6) + u0;
                const h2p q00 = ld_pair(&tile[r00]);
                const h2p q01 = ld_pair(&tile[r00 + SX]);
                const h2p q10 = ld_pair(&tile[r00 + SY * SX]);
                const h2p q11 = ld_pair(&tile[r00 + SY * SX + SX]);

                const float2 f00a = __half22float2(q00.a), f00b = __half22float2(q00.b);
                const float2 f01a = __half22float2(q01.a), f01b = __half22float2(q01.b);
                const float2 f10a = __half22float2(q10.a), f10b = __half22float2(q10.b);
                const float2 f11a = __half22float2(q11.a), f11b = __half22float2(q11.b);

                a0s[i] = w00 * (wx0 * f00a.x + wx1 * f00b.x)
                       + w01 * (wx0 * f01a.x + wx1 * f01b.x)
                       + w10 * (wx0 * f10a.x + wx1 * f10b.x)
                       + w11 * (wx0 * f11a.x + wx1 * f11b.x);
                a1s[i] = w00 * (wx0 * f00a.y + wx1 * f00b.y)
                       + w01 * (wx0 * f01a.y + wx1 * f01b.y)
                       + w10 * (wx0 * f10a.y + wx1 * f10b.y)
                       + w11 * (wx0 * f11a.y + wx1 * f11b.y);
            } else {
                // |flow| >= 4 near a tile face (P ~ 1e-5): exact fp32 global fallback
                const int zc0 = min(max(z0, 0), D - 1), zc1 = min(max(z0 + 1, 0), D - 1);
                const int yc0 = min(max(y0, 0), H - 1), yc1 = min(max(y0 + 1, 0), H - 1);
                const int xc0 = min(max(x0, 0), W - 1), xc1 = min(max(x0 + 1, 0), W - 1);
                const int g00 = (zc0 * H + yc0) * W, g01 = (zc0 * H + yc1) * W;
                const int g10 = (zc1 * H + yc0) * W, g11 = (zc1 * H + yc1) * W;
                a0s[i] = w00 * (wx0 * src0[g00 + xc0] + wx1 * src0[g00 + xc1])
                       + w01 * (wx0 * src0[g01 + xc0] + wx1 * src0[g01 + xc1])
                       + w10 * (wx0 * src0[g10 + xc0] + wx1 * src0[g10 + xc1])
                       + w11 * (wx0 * src0[g11 + xc0] + wx1 * src0[g11 + xc1]);
                a1s[i] = w00 * (wx0 * src1[g00 + xc0] + wx1 * src1[g00 + xc1])
                       + w01 * (wx0 * src1[g01 + xc0] + wx1 * src1[g01 + xc1])
                       + w10 * (wx0 * src1[g10 + xc0] + wx1 * src1[g10 + xc1])
                       + w11 * (wx0 * src1[g11 + xc0] + wx1 * src1[g11 + xc1]);
            }
        }

        f4 o0 = { a0s[0], a0s[1], a0s[2], a0s[3] };
        f4 o1 = { a1s[0], a1s[1], a1s[2], a1s[3] };
        st4f(out0 + vi, o0);
        st4f(out1 + vi, o1);
    };

    // ---- persistent pipeline (R5 skeleton, even 8 tiles/block) ----
    int tcur = blockIdx.x;
    issue(tcur);
    commit(tcur);
    shift_flow();
    __syncthreads();                      // buf ready

    #pragma unroll 1
    for (int k = 1; k < 8; ++k) {
        const int tnext = tcur + NBLK;
        issue(tnext);                     // loads fly during gather (compiler-scheduled)
        gather(tcur);
        __syncthreads();                  // all done reading buf
        commit(tnext);                    // vmcnt waits land here
        shift_flow();
        __syncthreads();                  // buf ready
        tcur = tnext;
    }
    gather(tcur);
}

extern "C" void kernel_launch(void* const* d_in, const int* in_sizes, int n_in,
                              void* d_out, int out_size, void* d_ws, size_t ws_size,
                              hipStream_t stream) {
    const float* src  = (const float*)d_in[0];
    const float* flow = (const float*)d_in[1];
    float* out = (float*)d_out;

    warp3d_r10_kernel<<<NBLK, NTHR, 0, stream>>>(src, flow, out);
}

// Round 12
// 62.093 us; speedup vs baseline: 1.2007x; 1.0207x over previous
//
#include <hip/hip_runtime.h>
#include <hip/hip_fp16.h>

// src:  [1,2,160,192,224] f32, flow: [1,3,160,192,224] f32, out: [1,2,160,192,224] f32
constexpr int D = 160, H = 192, W = 224;
constexpr int HW = H * W;
constexpr int N = D * HW;

// Tile 8x8x56 outputs, halo 4 -> staged 16x16x64 half2 = 64 KB, DOUBLE buffer (128 KB).
// Persistent 240 blocks x 8 tiles, ONE barrier per tile:
//   gather(t, p) | commit(t+1, p^1) | issue(t+2)->regs | sync
// commit(t+1) consumes loads issued a FULL TILE earlier -> vmcnt wait has ~8us slack.
constexpr int BZ = 8, BY = 8, BX = 56;
constexpr int HA = 4;
constexpr int SZ = 16, SY = 16, SX = 64;
constexpr int NTHR = 1024;
constexpr int NQ   = 896;                 // quad-owning threads (3584 vox / 4)
constexpr int NBLK = 240;
constexpr int NTY = 24;
constexpr int TPB = SZ * SY * SX;         // 16384 half2 = 64 KB per buffer

typedef float f4 __attribute__((ext_vector_type(4)));

struct h2p { __half2 a, b; };             // (ch0,ch1)@x , (ch0,ch1)@x+1
__device__ __forceinline__ h2p    ld_pair(const __half2* p){ h2p v; __builtin_memcpy(&v,p,8); return v; }
__device__ __forceinline__ void   st_pair(__half2* p, h2p v){ __builtin_memcpy(p,&v,8); }
__device__ __forceinline__ float2 ld2f(const float* p){ float2 v; __builtin_memcpy(&v,p,8); return v; }
__device__ __forceinline__ f4     ld4f(const float* p){ f4 v; __builtin_memcpy(&v,p,16); return v; }
__device__ __forceinline__ void   st4f(float* p, f4 v){ __builtin_memcpy(p,&v,16); }

__global__ __launch_bounds__(NTHR, 4) void warp3d_r11_kernel(
    const float* __restrict__ src,
    const float* __restrict__ flow,
    float* __restrict__ out)
{
    __shared__ __half2 tile[2][TPB];      // 128 KB

    const float* src0 = src;
    const float* src1 = src + N;
    const float* f0 = flow, * f1 = flow + N, * f2 = flow + 2 * N;
    float* out0 = out, * out1 = out + N;

    const int tid = threadIdx.x;
    const int u5  = tid & 31;             // staging x-pair lane
    const int rw  = tid >> 5;             // staging row worker 0..31 (8 rows each)
    const bool hasq = (tid < NQ);         // wave-uniform: waves 14,15 stage-only

    // ---- quad map (tile-independent): 4 consecutive x per thread ----
    const int qm = tid % 14, qd = tid / 14;       // qd in [0,64) when tid<896
    const int lx = qm << 2, ly = qd & 7, lz = qd >> 3;
    const int voffq = (lz * H + ly) * W + lx;
    const float lxf = (float)lx, lyf = (float)ly, lzf = (float)lz;

    float2 sA[8], sB[8];                  // staged src x-pairs (one set, recycled)
    f4 fz4n, fy4n, fx4n;                  // flow quad, next tile
    f4 fz4c, fy4c, fx4c;                  // flow quad, current tile

    // ---- issue: all global loads for tile t into registers, no waits ----
    auto issue = [&](int t) {
        const int bx = t & 3; const int q = t >> 2;
        const int by = q % NTY; const int bz = q / NTY;
        const int tz0 = bz * BZ - HA, ty0 = by * BY - HA, tx0 = bx * BX - HA;
        const int b  = tx0 + (u5 << 1);
        const int bc = min(max(b, 0), W - 2);
        #pragma unroll
        for (int j = 0; j < 8; ++j) {
            const int r  = rw + (j << 5);           // 0..255
            const int gz = min(max(tz0 + (r >> 4), 0), D - 1);
            const int gy = min(max(ty0 + (r & 15), 0), H - 1);
            const int ga = (gz * H + gy) * W + bc;
            sA[j] = ld2f(src0 + ga);
            sB[j] = ld2f(src1 + ga);
        }
        if (hasq) {
            const int vi = (bz * BZ * H + by * BY) * W + bx * BX + voffq;  // 16B aligned
            fz4n = ld4f(f0 + vi);
            fy4n = ld4f(f1 + vi);
            fx4n = ld4f(f2 + vi);
        }
    };

    // ---- commit: cvt + ds_write staged pairs into buffer p ----
    auto commit = [&](int t, int p) {
        const int bx = t & 3;
        const int tx0 = bx * BX - HA;
        const int b   = tx0 + (u5 << 1);
        const int bc  = min(max(b, 0), W - 2);
        const bool s0 = (min(max(b,     0), W - 1) > bc);   // x-edge component select
        const bool s1 = (min(max(b + 1, 0), W - 1) > bc);
        __half2* buf = tile[p];
        int ld = (rw << 6) + (u5 << 1);
        #pragma unroll
        for (int j = 0; j < 8; ++j) {
            const float a0 = s0 ? sA[j].y : sA[j].x;
            const float a1 = s1 ? sA[j].y : sA[j].x;
            const float c0 = s0 ? sB[j].y : sB[j].x;
            const float c1 = s1 ? sB[j].y : sB[j].x;
            h2p v;
            v.a = __floats2half2_rn(a0, c0);
            v.b = __floats2half2_rn(a1, c1);
            st_pair(&buf[ld], v);
            ld += 2048;                                     // 32 rows * 64
        }
    };

    auto shift_flow = [&]() { fz4c = fz4n; fy4c = fy4n; fx4c = fx4n; };

    // ---- gather: one x-quad per thread (tid<896), float4 out stores ----
    auto gather = [&](int t, int p) {
        if (!hasq) return;
        const int bx = t & 3; const int q = t >> 2;
        const int by = q % NTY; const int bz = q / NTY;
        const int tz0 = bz * BZ - HA, ty0 = by * BY - HA, tx0 = bx * BX - HA;
        const int vi = (bz * BZ * H + by * BY) * W + bx * BX + voffq;
        const __half2* buf = tile[p];

        const float pz_b = (float)(bz * BZ) + lzf;
        const float py_b = (float)(by * BY) + lyf;
        const float px_b = (float)(bx * BX) + lxf;

        float a0s[4], a1s[4];

        #pragma unroll
        for (int i = 0; i < 4; ++i) {
            const float pz = fz4c[i] + pz_b;
            const float py = fy4c[i] + py_b;
            const float px = fx4c[i] + (px_b + (float)i);

            const float z0f = floorf(pz), y0f = floorf(py), x0f = floorf(px);
            const float fz = pz - z0f, fy = py - y0f, fx = px - x0f;
            const int z0 = (int)z0f, y0 = (int)y0f, x0 = (int)x0f;

            // zeros padding folded into per-axis weights (validity on GLOBAL coords)
            const float wz0 = ((unsigned)z0       < (unsigned)D) ? (1.0f - fz) : 0.0f;
            const float wz1 = ((unsigned)(z0 + 1) < (unsigned)D) ? fz          : 0.0f;
            const float wy0 = ((unsigned)y0       < (unsigned)H) ? (1.0f - fy) : 0.0f;
            const float wy1 = ((unsigned)(y0 + 1) < (unsigned)H) ? fy          : 0.0f;
            const float wx0 = ((unsigned)x0       < (unsigned)W) ? (1.0f - fx) : 0.0f;
            const float wx1 = ((unsigned)(x0 + 1) < (unsigned)W) ? fx          : 0.0f;

            const float w00 = wz0 * wy0, w01 = wz0 * wy1;
            const float w10 = wz1 * wy0, w11 = wz1 * wy1;

            const int a0 = z0 - tz0;
            const int b0 = y0 - ty0;
            const int u0 = x0 - tx0;
            const bool intile = ((unsigned)a0 < (unsigned)(SZ - 1)) &&
                                ((unsigned)b0 < (unsigned)(SY - 1)) &&
                                ((unsigned)u0 < (unsigned)(SX - 1));

            if (intile) {
                const int r00 = (((a0 << 4) + b0) << 6) + u0;
                const h2p q00 = ld_pair(&buf[r00]);
                const h2p q01 = ld_pair(&buf[r00 + SX]);
                const h2p q10 = ld_pair(&buf[r00 + SY * SX]);
                const h2p q11 = ld_pair(&buf[r00 + SY * SX + SX]);

                const float2 f00a = __half22float2(q00.a), f00b = __half22float2(q00.b);
                const float2 f01a = __half22float2(q01.a), f01b = __half22float2(q01.b);
                const float2 f10a = __half22float2(q10.a), f10b = __half22float2(q10.b);
                const float2 f11a = __half22float2(q11.a), f11b = __half22float2(q11.b);

                a0s[i] = w00 * (wx0 * f00a.x + wx1 * f00b.x)
                       + w01 * (wx0 * f01a.x + wx1 * f01b.x)
                       + w10 * (wx0 * f10a.x + wx1 * f10b.x)
                       + w11 * (wx0 * f11a.x + wx1 * f11b.x);
                a1s[i] = w00 * (wx0 * f00a.y + wx1 * f00b.y)
                       + w01 * (wx0 * f01a.y + wx1 * f01b.y)
                       + w10 * (wx0 * f10a.y + wx1 * f10b.y)
                       + w11 * (wx0 * f11a.y + wx1 * f11b.y);
            } else {
                // |flow| >= 4 near a tile face (P ~ 1e-5): exact fp32 global fallback
                const int zc0 = min(max(z0, 0), D - 1), zc1 = min(max(z0 + 1, 0), D - 1);
                const int yc0 = min(max(y0, 0), H - 1), yc1 = min(max(y0 + 1, 0), H - 1);
                const int xc0 = min(max(x0, 0), W - 1), xc1 = min(max(x0 + 1, 0), W - 1);
                const int g00 = (zc0 * H + yc0) * W, g01 = (zc0 * H + yc1) * W;
                const int g10 = (zc1 * H + yc0) * W, g11 = (zc1 * H + yc1) * W;
                a0s[i] = w00 * (wx0 * src0[g00 + xc0] + wx1 * src0[g00 + xc1])
                       + w01 * (wx0 * src0[g01 + xc0] + wx1 * src0[g01 + xc1])
                       + w10 * (wx0 * src0[g10 + xc0] + wx1 * src0[g10 + xc1])
                       + w11 * (wx0 * src0[g11 + xc0] + wx1 * src0[g11 + xc1]);
                a1s[i] = w00 * (wx0 * src1[g00 + xc0] + wx1 * src1[g00 + xc1])
                       + w01 * (wx0 * src1[g01 + xc0] + wx1 * src1[g01 + xc1])
                       + w10 * (wx0 * src1[g10 + xc0] + wx1 * src1[g10 + xc1])
                       + w11 * (wx0 * src1[g11 + xc0] + wx1 * src1[g11 + xc1]);
            }
        }

        f4 o0 = { a0s[0], a0s[1], a0s[2], a0s[3] };
        f4 o1 = { a1s[0], a1s[1], a1s[2], a1s[3] };
        st4f(out0 + vi, o0);
        st4f(out1 + vi, o1);
    };

    // ---- persistent pipeline: dbuf, ONE barrier/tile ----
    int tcur = blockIdx.x;
    issue(tcur);                          // src(t0) -> regs, flow(t0) -> n
    commit(tcur, 0);                      // buf0 (vmcnt waits here, cold)
    shift_flow();                         // flow(t0) -> c
    issue(tcur + NBLK);                   // src(t1) -> regs, flow(t1) -> n
    __syncthreads();                      // buf0 ready

    int p = 0;
    #pragma unroll 1
    for (int k = 0; k < 7; ++k) {
        const int tnext = tcur + NBLK;
        gather(tcur, p);                  // read buf p
        commit(tnext, p ^ 1);             // write other buffer; loads are a tile old
        shift_flow();                     // flow(tnext) -> c
        if (k < 6) issue(tnext + NBLK);   // refill regs for tile t+2
        __syncthreads();                  // buf p^1 ready; all reads of p done
        tcur = tnext;
        p ^= 1;
    }
    gather(tcur, p);
}

extern "C" void kernel_launch(void* const* d_in, const int* in_sizes, int n_in,
                              void* d_out, int out_size, void* d_ws, size_t ws_size,
                              hipStream_t stream) {
    const float* src  = (const float*)d_in[0];
    const float* flow = (const float*)d_in[1];
    float* out = (float*)d_out;

    warp3d_r11_kernel<<<NBLK, NTHR, 0, stream>>>(src, flow, out);
}

// Round 13
// 60.588 us; speedup vs baseline: 1.2305x; 1.0248x over previous
//
#include <hip/hip_runtime.h>
#include <hip/hip_fp16.h>

// src:  [1,2,160,192,224] f32, flow: [1,3,160,192,224] f32, out: [1,2,160,192,224] f32
constexpr int D = 160, H = 192, W = 224;
constexpr int HW = H * W;
constexpr int N = D * HW;

// Tile 8x8x32 outputs, halo 4 -> staged 16x16x40 half2 = 40 KB -> 4 blocks/CU.
// 512 threads (8 waves), <=64 VGPR -> up to 32 waves/CU. Cross-BLOCK TLP hides
// staging latency (no intra-block pipeline needed). Grid (7,24,20), 1 tile/block.
constexpr int BZ = 8, BY = 8, BX = 32;
constexpr int HA = 4;
constexpr int SZ = 16, SY = 16, SX = 40;   // staged extents (half2 elements in x)
constexpr int SXP = 20;                     // staged x-pairs per row
constexpr int NTHR = 512;
constexpr int NPAIR = SZ * SY * SXP;        // 5120 pairs, 10 per thread
constexpr int TPB = SZ * SY * SX;           // 10240 half2 = 40 KB

typedef float f4 __attribute__((ext_vector_type(4)));

struct h2p { __half2 a, b; };               // (ch0,ch1)@x , (ch0,ch1)@x+1
__device__ __forceinline__ h2p    ld_pair(const __half2* p){ h2p v; __builtin_memcpy(&v,p,8); return v; }
__device__ __forceinline__ void   st_pair(__half2* p, h2p v){ __builtin_memcpy(p,&v,8); }
__device__ __forceinline__ float2 ld2f(const float* p){ float2 v; __builtin_memcpy(&v,p,8); return v; }
__device__ __forceinline__ f4     ld4f(const float* p){ f4 v; __builtin_memcpy(&v,p,16); return v; }
__device__ __forceinline__ void   st4f(float* p, f4 v){ __builtin_memcpy(p,&v,16); }

__global__ __launch_bounds__(NTHR, 8) void warp3d_r12_kernel(
    const float* __restrict__ src,
    const float* __restrict__ flow,
    float* __restrict__ out)
{
    __shared__ __half2 tile[TPB];           // 40 KB

    const float* src0 = src;
    const float* src1 = src + N;
    const float* f0 = flow, * f1 = flow + N, * f2 = flow + 2 * N;
    float* out0 = out, * out1 = out + N;

    const int tid = threadIdx.x;
    const int bx = blockIdx.x, by = blockIdx.y, bz = blockIdx.z;
    const int tz0 = bz * BZ - HA, ty0 = by * BY - HA, tx0 = bx * BX - HA;
    const int tbase = (bz * BZ * H + by * BY) * W + bx * BX;

    // ---- flow quad for this thread (4 consecutive x), 16B-aligned f4 loads ----
    const int qm = tid & 7, qd = tid >> 3;  // qd in [0,64)
    const int lx = qm << 2, ly = qd & 7, lz = qd >> 3;
    const int vi = tbase + (lz * H + ly) * W + lx;
    const f4 fz4 = ld4f(f0 + vi);
    const f4 fy4 = ld4f(f1 + vi);
    const f4 fx4 = ld4f(f2 + vi);

    // ---- stage: 10 x-pairs per thread (flat index, coalesced-ish rows) ----
    #pragma unroll 2
    for (int k = 0; k < NPAIR / NTHR; ++k) {
        const int pi  = tid + k * NTHR;
        const int row = pi / SXP;           // const-div -> magic mul
        const int col = pi - row * SXP;
        const int s = row >> 4, t = row & 15;
        const int gz = min(max(tz0 + s, 0), D - 1);
        const int gy = min(max(ty0 + t, 0), H - 1);
        const int b  = tx0 + (col << 1);
        const int bc = min(max(b, 0), W - 2);
        const bool s0 = (min(max(b,     0), W - 1) > bc);   // x-edge component select
        const bool s1 = (min(max(b + 1, 0), W - 1) > bc);
        const int ga = (gz * H + gy) * W + bc;
        const float2 a = ld2f(src0 + ga);
        const float2 c = ld2f(src1 + ga);
        h2p v;
        v.a = __floats2half2_rn(s0 ? a.y : a.x, s0 ? c.y : c.x);
        v.b = __floats2half2_rn(s1 ? a.y : a.x, s1 ? c.y : c.x);
        st_pair(&tile[row * SX + (col << 1)], v);
    }
    __syncthreads();

    // ---- gather: one x-quad per thread, float4 out stores ----
    const float pz_b = (float)(bz * BZ + lz);
    const float py_b = (float)(by * BY + ly);
    const float px_b = (float)(bx * BX + lx);

    float a0s[4], a1s[4];

    #pragma unroll
    for (int i = 0; i < 4; ++i) {
        const float pz = fz4[i] + pz_b;
        const float py = fy4[i] + py_b;
        const float px = fx4[i] + (px_b + (float)i);

        const float z0f = floorf(pz), y0f = floorf(py), x0f = floorf(px);
        const float fz = pz - z0f, fy = py - y0f, fx = px - x0f;
        const int z0 = (int)z0f, y0 = (int)y0f, x0 = (int)x0f;

        // zeros padding folded into per-axis weights (validity on GLOBAL coords)
        const float wz0 = ((unsigned)z0       < (unsigned)D) ? (1.0f - fz) : 0.0f;
        const float wz1 = ((unsigned)(z0 + 1) < (unsigned)D) ? fz          : 0.0f;
        const float wy0 = ((unsigned)y0       < (unsigned)H) ? (1.0f - fy) : 0.0f;
        const float wy1 = ((unsigned)(y0 + 1) < (unsigned)H) ? fy          : 0.0f;
        const float wx0 = ((unsigned)x0       < (unsigned)W) ? (1.0f - fx) : 0.0f;
        const float wx1 = ((unsigned)(x0 + 1) < (unsigned)W) ? fx          : 0.0f;

        const float w00 = wz0 * wy0, w01 = wz0 * wy1;
        const float w10 = wz1 * wy0, w11 = wz1 * wy1;

        const int a0 = z0 - tz0;
        const int b0 = y0 - ty0;
        const int u0 = x0 - tx0;
        const bool intile = ((unsigned)a0 < (unsigned)(SZ - 1)) &&
                            ((unsigned)b0 < (unsigned)(SY - 1)) &&
                            ((unsigned)u0 < (unsigned)(SX - 1));

        if (intile) {
            const int r00 = (a0 * SY + b0) * SX + u0;
            const h2p q00 = ld_pair(&tile[r00]);
            const h2p q01 = ld_pair(&tile[r00 + SX]);
            const h2p q10 = ld_pair(&tile[r00 + SY * SX]);
            const h2p q11 = ld_pair(&tile[r00 + SY * SX + SX]);

            const float2 f00a = __half22float2(q00.a), f00b = __half22float2(q00.b);
            const float2 f01a = __half22float2(q01.a), f01b = __half22float2(q01.b);
            const float2 f10a = __half22float2(q10.a), f10b = __half22float2(q10.b);
            const float2 f11a = __half22float2(q11.a), f11b = __half22float2(q11.b);

            a0s[i] = w00 * (wx0 * f00a.x + wx1 * f00b.x)
                   + w01 * (wx0 * f01a.x + wx1 * f01b.x)
                   + w10 * (wx0 * f10a.x + wx1 * f10b.x)
                   + w11 * (wx0 * f11a.x + wx1 * f11b.x);
            a1s[i] = w00 * (wx0 * f00a.y + wx1 * f00b.y)
                   + w01 * (wx0 * f01a.y + wx1 * f01b.y)
                   + w10 * (wx0 * f10a.y + wx1 * f10b.y)
                   + w11 * (wx0 * f11a.y + wx1 * f11b.y);
        } else {
            // |flow| >= 4 near a tile face (P ~ 1e-5): exact fp32 global fallback
            const int zc0 = min(max(z0, 0), D - 1), zc1 = min(max(z0 + 1, 0), D - 1);
            const int yc0 = min(max(y0, 0), H - 1), yc1 = min(max(y0 + 1, 0), H - 1);
            const int xc0 = min(max(x0, 0), W - 1), xc1 = min(max(x0 + 1, 0), W - 1);
            const int g00 = (zc0 * H + yc0) * W, g01 = (zc0 * H + yc1) * W;
            const int g10 = (zc1 * H + yc0) * W, g11 = (zc1 * H + yc1) * W;
            a0s[i] = w00 * (wx0 * src0[g00 + xc0] + wx1 * src0[g00 + xc1])
                   + w01 * (wx0 * src0[g01 + xc0] + wx1 * src0[g01 + xc1])
                   + w10 * (wx0 * src0[g10 + xc0] + wx1 * src0[g10 + xc1])
                   + w11 * (wx0 * src0[g11 + xc0] + wx1 * src0[g11 + xc1]);
            a1s[i] = w00 * (wx0 * src1[g00 + xc0] + wx1 * src1[g00 + xc1])
                   + w01 * (wx0 * src1[g01 + xc0] + wx1 * src1[g01 + xc1])
                   + w10 * (wx0 * src1[g10 + xc0] + wx1 * src1[g10 + xc1])
                   + w11 * (wx0 * src1[g11 + xc0] + wx1 * src1[g11 + xc1]);
        }
    }

    f4 o0 = { a0s[0], a0s[1], a0s[2], a0s[3] };
    f4 o1 = { a1s[0], a1s[1], a1s[2], a1s[3] };
    st4f(out0 + vi, o0);
    st4f(out1 + vi, o1);
}

extern "C" void kernel_launch(void* const* d_in, const int* in_sizes, int n_in,
                              void* d_out, int out_size, void* d_ws, size_t ws_size,
                              hipStream_t stream) {
    const float* src  = (const float*)d_in[0];
    const float* flow = (const float*)d_in[1];
    float* out = (float*)d_out;

    dim3 grid(W / BX, H / BY, D / BZ);      // 7 x 24 x 20 = 3360 blocks
    warp3d_r12_kernel<<<grid, NTHR, 0, stream>>>(src, flow, out);
}